// Round 6
// baseline (108.703 us; speedup 1.0000x reference)
//
#include <hip/hip_runtime.h>
#include <hip/hip_bf16.h>
#include <stdint.h>

#define IN_DIM  1024
#define LOW     128
#define OUT_DIM 1024
#define BATCH   8
#define SEQ     2048

typedef unsigned short u16;
typedef short bf16x8 __attribute__((ext_vector_type(8)));
typedef unsigned short u16x4 __attribute__((ext_vector_type(4)));
typedef float f32x4 __attribute__((ext_vector_type(4)));

__device__ __forceinline__ u16 f2bf(float f) {
    union { float f; uint32_t u; } v;
    v.f = f;
    uint32_t u = v.u;
    return (u16)((u + 0x7fffu + ((u >> 16) & 1u)) >> 16);
}

// ---------------------------------------------------------------------------
// gen_w v5: barrier-free streaming + butterfly reduce (m13-copy shape).
//   D half (bid<1024):  DgT[b][l][d] = dot(Dm[d*128+l][:], k[b][:])
//   U half (bid>=1024): UgT[b][o][l] = dot(Um[l*1024+o][:], k[b][:])
// Block = 16 m x 8 n = 128 p-rows = 64 KB, read in ONE shot:
//   wave w owns m = m0+w*4..+3; per m, 4 x 1KB contiguous loads (2 rows each).
//   All 16 loads issued before any compute -> 16 KB/wave in flight.
// Lane map: q=lane&31 owns cols 4q..4q+3 (k in 8 f32x4 regs), h=lane>>5 = row.
// Reduce: 5-stage shfl_xor within 32-lane half -> every lane has row sums.
// tb[b][n][m] 2KB -> one barrier -> coalesced 8B flush.
// grid 2048. No main-loop barriers, no LDS staging of M.
// ---------------------------------------------------------------------------
__global__ __launch_bounds__(256) void gen_w(const float* __restrict__ Dm,
                                             const float* __restrict__ Um,
                                             const float* __restrict__ kv,
                                             u16* __restrict__ DgT,
                                             u16* __restrict__ UgT) {
    __shared__ u16 tb[8 * 8 * 16];   // [b][n-local][m-local], 2 KB

    int t = threadIdx.x;
    int bid = blockIdx.x;
    bool isU = bid >= 1024;
    int rb = isU ? (bid - 1024) : bid;
    const float* src = isU ? Um : Dm;
    u16* outp = isU ? UgT : DgT;
    int NTOT = isU ? 1024 : 128;   // p = m*NTOT + n
    int MTOT = isU ? 128 : 1024;   // output contiguous-run dim
    int sh = isU ? 7 : 4;
    int m0 = (rb >> sh) * 16;
    int n0 = (rb & ((1 << sh) - 1)) * 8;

    int w = t >> 6, lane = t & 63;
    int q = lane & 31, h = lane >> 5;

    // k registers: lane q holds k[b][4q..4q+3] for all 8 batches (32 VGPRs)
    f32x4 kq[8];
#pragma unroll
    for (int b = 0; b < 8; ++b)
        kq[b] = *(const f32x4*)(kv + b * LOW + q * 4);

    // issue all 16 x 1KB loads (independent, stay in flight together)
    f32x4 L[4][4];
#pragma unroll
    for (int mj = 0; mj < 4; ++mj) {
        int m = m0 + w * 4 + mj;
        const float* bp = src + ((size_t)m * NTOT + n0) * 128 + lane * 4;
#pragma unroll
        for (int j = 0; j < 4; ++j)
            L[mj][j] = *(const f32x4*)(bp + j * 256);   // rows n0+2j, n0+2j+1
    }

#pragma unroll
    for (int mj = 0; mj < 4; ++mj) {
        int mloc = w * 4 + mj;
#pragma unroll
        for (int j = 0; j < 4; ++j) {
            f32x4 v = L[mj][j];
            float a[8];
#pragma unroll
            for (int b = 0; b < 8; ++b)
                a[b] = v.x * kq[b].x + v.y * kq[b].y + v.z * kq[b].z + v.w * kq[b].w;
            // reduce over 32 lanes (cols) within each half; xor<=16 stays in half
#pragma unroll
            for (int s = 1; s <= 16; s <<= 1)
#pragma unroll
                for (int b = 0; b < 8; ++b)
                    a[b] += __shfl_xor(a[b], s);
            // half h holds total of row n-local (2j+h); lanes q==b write batch b
            int nl = 2 * j + h;
#pragma unroll
            for (int b = 0; b < 8; ++b)
                if (q == b)
                    tb[b * 128 + nl * 16 + mloc] = f2bf(a[b]);
        }
    }
    __syncthreads();

    // coalesced flush: 64 (b,n') pairs x 32B (16 m), 8B per thread
    int pair = t >> 2, q4 = t & 3;
    int bw = pair >> 3, np = pair & 7;
    u16x4 vv = *(const u16x4*)(tb + bw * 128 + np * 16 + q4 * 4);
    *(u16x4*)(outp + ((size_t)(bw * NTOT + n0 + np)) * MTOT + m0 + q4 * 4) = vv;
}

// ---------------------------------------------------------------------------
// fc1: h[b][s][l] = relu( sum_d x[b][s][d] * D[b][d][l] )  -> bf16
// tile: M=32 (s), N=128 (all l), K-loop 1024 step 64. grid = 8*64 = 512
// ---------------------------------------------------------------------------
__global__ __launch_bounds__(256) void fc1(const float* __restrict__ x,
                                           const u16* __restrict__ DgT,
                                           u16* __restrict__ h) {
    __shared__ u16 As[32][72];
    __shared__ u16 Bs[128][72];
    int t = threadIdx.x;
    int bid = blockIdx.x;
    int b = bid >> 6, st = bid & 63;
    int s0 = st * 32;
    const float* xb = x + ((size_t)b * SEQ + s0) * IN_DIM;
    const u16* Db = DgT + (size_t)b * LOW * IN_DIM;

    int w = t >> 6, lane = t & 63;
    int wm = w >> 1, wn = w & 1;
    int lr = lane & 15, hi = lane >> 4;

    f32x4 acc[4];
#pragma unroll
    for (int nf = 0; nf < 4; ++nf) acc[nf] = (f32x4){0.f, 0.f, 0.f, 0.f};

    int ar = t >> 3, ac = t & 7;
    int brt = t >> 3, bc = t & 7;

    for (int kt = 0; kt < IN_DIM / 64; ++kt) {
        int k0 = kt * 64;
#pragma unroll
        for (int i = 0; i < 2; ++i) {
            float4 v = *(const float4*)(xb + (size_t)ar * IN_DIM + k0 + ac * 4 + i * 32);
            u16x4 o;
            o.x = f2bf(v.x); o.y = f2bf(v.y); o.z = f2bf(v.z); o.w = f2bf(v.w);
            *(u16x4*)(&As[ar][ac * 4 + i * 32]) = o;
        }
#pragma unroll
        for (int i = 0; i < 4; ++i) {
            int row = brt + 32 * i;
            bf16x8 v = *(const bf16x8*)(Db + (size_t)row * IN_DIM + k0 + bc * 8);
            *(bf16x8*)(&Bs[row][bc * 8]) = v;
        }
        __syncthreads();
#pragma unroll
        for (int ks = 0; ks < 2; ++ks) {
            int kk = ks * 32 + hi * 8;
            bf16x8 af = *(const bf16x8*)(&As[wm * 16 + lr][kk]);
#pragma unroll
            for (int nf = 0; nf < 4; ++nf) {
                bf16x8 bf = *(const bf16x8*)(&Bs[wn * 64 + nf * 16 + lr][kk]);
                acc[nf] = __builtin_amdgcn_mfma_f32_16x16x32_bf16(af, bf, acc[nf], 0, 0, 0);
            }
        }
        __syncthreads();
    }
    u16* hb = h + ((size_t)b * SEQ + s0) * LOW;
#pragma unroll
    for (int nf = 0; nf < 4; ++nf) {
        int col = wn * 64 + nf * 16 + lr;
#pragma unroll
        for (int j = 0; j < 4; ++j) {
            int rrow = wm * 16 + hi * 4 + j;
            hb[(size_t)rrow * LOW + col] = f2bf(fmaxf(acc[nf][j], 0.f));
        }
    }
}

// ---------------------------------------------------------------------------
// fc2: out[b][s][o] = sum_l h[b][s][l] * U[b][l][o]   (f32 out)
// tile: 128x128, K=128 staged once. grid = 8*16*8 = 1024
// ---------------------------------------------------------------------------
__global__ __launch_bounds__(256) void fc2(const u16* __restrict__ h,
                                           const u16* __restrict__ UgT,
                                           float* __restrict__ out) {
    __shared__ u16 As[128 * 128];
    __shared__ u16 Bs[128 * 128];
    int t = threadIdx.x;
    int bid = blockIdx.x;
    int b = bid >> 7, st = (bid >> 3) & 15, ot = bid & 7;
    int s0 = st * 128, o0 = ot * 128;
    const u16* hb = h + ((size_t)b * SEQ + s0) * LOW;
    const u16* Ub = UgT + ((size_t)b * OUT_DIM + o0) * LOW;

#pragma unroll
    for (int i = 0; i < 8; ++i) {
        int ch = i * 256 + t;
        int row = ch >> 4, c = ch & 15;
        int swc = c ^ (row & 7);
        *(bf16x8*)(As + row * 128 + swc * 8) = *(const bf16x8*)(hb + (size_t)ch * 8);
        *(bf16x8*)(Bs + row * 128 + swc * 8) = *(const bf16x8*)(Ub + (size_t)ch * 8);
    }
    __syncthreads();

    int w = t >> 6, lane = t & 63;
    int wm = w >> 1, wn = w & 1;
    int lr = lane & 15, lkc = (lane >> 4);

    f32x4 acc[4][4];
#pragma unroll
    for (int mf = 0; mf < 4; ++mf)
#pragma unroll
        for (int nf = 0; nf < 4; ++nf)
            acc[mf][nf] = (f32x4){0.f, 0.f, 0.f, 0.f};

#pragma unroll
    for (int ks = 0; ks < 4; ++ks) {
        bf16x8 af[4], bfr[4];
#pragma unroll
        for (int mf = 0; mf < 4; ++mf) {
            int row = wm * 64 + mf * 16 + lr;
            int swc = (ks * 4 + lkc) ^ (row & 7);
            af[mf] = *(const bf16x8*)(As + row * 128 + swc * 8);
        }
#pragma unroll
        for (int nf = 0; nf < 4; ++nf) {
            int row = wn * 64 + nf * 16 + lr;
            int swc = (ks * 4 + lkc) ^ (row & 7);
            bfr[nf] = *(const bf16x8*)(Bs + row * 128 + swc * 8);
        }
#pragma unroll
        for (int mf = 0; mf < 4; ++mf)
#pragma unroll
            for (int nf = 0; nf < 4; ++nf)
                acc[mf][nf] = __builtin_amdgcn_mfma_f32_16x16x32_bf16(
                    af[mf], bfr[nf], acc[mf][nf], 0, 0, 0);
    }

    float* ob = out + ((size_t)b * SEQ + s0) * OUT_DIM + o0;
#pragma unroll
    for (int mf = 0; mf < 4; ++mf)
#pragma unroll
        for (int nf = 0; nf < 4; ++nf) {
            int col = wn * 64 + nf * 16 + lr;
#pragma unroll
            for (int j = 0; j < 4; ++j) {
                int rrow = wm * 64 + mf * 16 + (lane >> 4) * 4 + j;
                ob[(size_t)rrow * OUT_DIM + col] = acc[mf][nf][j];
            }
        }
}

extern "C" void kernel_launch(void* const* d_in, const int* in_sizes, int n_in,
                              void* d_out, int out_size, void* d_ws, size_t ws_size,
                              hipStream_t stream) {
    const float* x  = (const float*)d_in[0];
    const float* kv = (const float*)d_in[1];
    const float* Dm = (const float*)d_in[2];
    const float* Um = (const float*)d_in[3];
    float* out = (float*)d_out;

    u16* DgT = (u16*)d_ws;                                   // 2 MB
    u16* UgT = DgT + (size_t)BATCH * LOW * IN_DIM;           // 2 MB
    u16* hbuf = UgT + (size_t)BATCH * OUT_DIM * LOW;         // 4 MB

    gen_w<<<dim3(2048), dim3(256), 0, stream>>>(Dm, Um, kv, DgT, UgT);
    fc1<<<dim3(512), dim3(256), 0, stream>>>(x, DgT, hbuf);
    fc2<<<dim3(1024), dim3(256), 0, stream>>>(hbuf, UgT, out);
}

// Round 7
// 69.513 us; speedup vs baseline: 1.5638x; 1.5638x over previous
//
#include <hip/hip_runtime.h>
#include <hip/hip_bf16.h>
#include <stdint.h>

#define IN_DIM  1024
#define LOW     128
#define OUT_DIM 1024
#define BATCH   8
#define SEQ     2048

typedef unsigned short u16;
typedef short bf16x8 __attribute__((ext_vector_type(8)));
typedef unsigned short u16x4 __attribute__((ext_vector_type(4)));
typedef float f32x4 __attribute__((ext_vector_type(4)));

__device__ __forceinline__ u16 f2bf(float f) {
    union { float f; uint32_t u; } v;
    v.f = f;
    uint32_t u = v.u;
    return (u16)((u + 0x7fffu + ((u >> 16) & 1u)) >> 16);
}

// ---------------------------------------------------------------------------
// gen_w v6: MFMA fed DIRECTLY from global — zero LDS on the M-stream.
//   D half (bid<512):  DgT[b][l][d] = dot(Dm[d*128+l][:], k[b][:])
//   U half (bid>=512): UgT[b][o][l] = dot(Um[l*1024+o][:], k[b][:])
// Skinny GEMM C[p][b] = M[p][:] @ k[b][:]^T, mfma_f32_16x16x32_bf16 (math
// verified in R5). Block = 256 p-rows (32 m x 8 n), 4 waves; wave w owns
// 64 rows = 4 tiles of 16. Per tile: A-frag loaded straight from global
// (lane lr=A-row, hi=k-group; 4 lanes cover each 128B line contiguously),
// cvt f32->bf16, 4 MFMA (k=128). B-frag = bf16(k) constant in 16 VGPRs.
// 2-tile software pipeline (16 dwordx4/wave in flight, NO barriers in loop
// -> compiler emits counted vmcnt). Results -> 4KB tb, one barrier,
// coalesced flush (identical to R5's verified path). grid 1024.
// ---------------------------------------------------------------------------
__global__ __launch_bounds__(256) void gen_w(const float* __restrict__ Dm,
                                             const float* __restrict__ Um,
                                             const float* __restrict__ kv,
                                             u16* __restrict__ DgT,
                                             u16* __restrict__ UgT) {
    __shared__ u16 tb[8 * 8 * 32];   // [b][n-local 8][m-local 32], 4 KB

    int t = threadIdx.x;
    int bid = blockIdx.x;
    bool isU = bid >= 512;
    int rb = isU ? (bid - 512) : bid;
    const float* src = isU ? Um : Dm;
    u16* outp = isU ? UgT : DgT;
    int NTOT = isU ? 1024 : 128;   // p = m*NTOT + n
    int MTOT = isU ? 128 : 1024;   // output contiguous-run dim
    int sh = isU ? 7 : 4;
    int m0 = (rb >> sh) * 32;
    int n0 = (rb & ((1 << sh) - 1)) * 8;

    int lane = t & 63, w = t >> 6;
    int lr = lane & 15;            // A-row / C-col (batch) index
    int hi = lane >> 4;            // k-group / C row-group

    // B-fragments: bf16(k[batch=lr][k]) for k = ks*32 + hi*8 + j; cols 8..15 = 0
    bf16x8 bfrag[4];
#pragma unroll
    for (int ks = 0; ks < 4; ++ks)
#pragma unroll
        for (int j = 0; j < 8; ++j) {
            float kvf = (lr < 8) ? kv[lr * LOW + ks * 32 + hi * 8 + j] : 0.f;
            bfrag[ks][j] = (short)f2bf(kvf);
        }

    // per-lane A base: tile tau covers block-local rows w*64+tau*16 + (0..15)
    // lane lr's p-row: m = m0 + w*8 + tau*2 + (lr>>3), n = n0 + (lr&7)
    const float* abase = src +
        ((size_t)(m0 + w * 8 + (lr >> 3)) * NTOT + n0 + (lr & 7)) * 128 + hi * 8;
    size_t tstep = (size_t)2 * NTOT * 128;   // floats per tau step

#define ISSUE(Lb, tau)                                                        \
    {                                                                         \
        const float* rp = abase + (size_t)(tau) * tstep;                      \
        _Pragma("unroll")                                                     \
        for (int ks = 0; ks < 4; ++ks) {                                      \
            Lb[2 * ks]     = *(const f32x4*)(rp + ks * 32);                   \
            Lb[2 * ks + 1] = *(const f32x4*)(rp + ks * 32 + 4);               \
        }                                                                     \
    }

#define COMPUTE(Lb, tau)                                                      \
    {                                                                         \
        f32x4 acc = (f32x4){0.f, 0.f, 0.f, 0.f};                              \
        _Pragma("unroll")                                                     \
        for (int ks = 0; ks < 4; ++ks) {                                      \
            f32x4 v0 = Lb[2 * ks], v1 = Lb[2 * ks + 1];                       \
            bf16x8 afr;                                                       \
            afr[0] = (short)f2bf(v0.x); afr[1] = (short)f2bf(v0.y);           \
            afr[2] = (short)f2bf(v0.z); afr[3] = (short)f2bf(v0.w);           \
            afr[4] = (short)f2bf(v1.x); afr[5] = (short)f2bf(v1.y);           \
            afr[6] = (short)f2bf(v1.z); afr[7] = (short)f2bf(v1.w);           \
            acc = __builtin_amdgcn_mfma_f32_16x16x32_bf16(afr, bfrag[ks],     \
                                                          acc, 0, 0, 0);      \
        }                                                                     \
        if (lr < 8) {                                                         \
            _Pragma("unroll")                                                 \
            for (int j = 0; j < 4; ++j) {                                     \
                int r = hi * 4 + j;                                           \
                int mm = w * 8 + (tau) * 2 + (r >> 3);                        \
                tb[lr * 256 + (r & 7) * 32 + mm] = f2bf(acc[j]);              \
            }                                                                 \
        }                                                                     \
    }

    f32x4 LA[8], LB[8];
    ISSUE(LA, 0)
    ISSUE(LB, 1)
    COMPUTE(LA, 0)
    ISSUE(LA, 2)
    COMPUTE(LB, 1)
    ISSUE(LB, 3)
    COMPUTE(LA, 2)
    COMPUTE(LB, 3)
#undef ISSUE
#undef COMPUTE

    __syncthreads();   // tb visible

    // coalesced flush: 64 chunks (b,n') x 64B (32 m)  [identical to R5]
    int c64 = t >> 2, q4 = t & 3;
    int bw = c64 >> 3, np = c64 & 7;
    bf16x8 v = *(const bf16x8*)(tb + bw * 256 + np * 32 + q4 * 8);
    *(bf16x8*)(outp + ((size_t)(bw * NTOT + n0 + np)) * MTOT + m0 + q4 * 8) = v;
}

// ---------------------------------------------------------------------------
// fc1: h[b][s][l] = relu( sum_d x[b][s][d] * D[b][d][l] )  -> bf16
// tile: M=32 (s), N=128 (all l), K-loop 1024 step 64. grid = 8*64 = 512
// ---------------------------------------------------------------------------
__global__ __launch_bounds__(256) void fc1(const float* __restrict__ x,
                                           const u16* __restrict__ DgT,
                                           u16* __restrict__ h) {
    __shared__ u16 As[32][72];
    __shared__ u16 Bs[128][72];
    int t = threadIdx.x;
    int bid = blockIdx.x;
    int b = bid >> 6, st = bid & 63;
    int s0 = st * 32;
    const float* xb = x + ((size_t)b * SEQ + s0) * IN_DIM;
    const u16* Db = DgT + (size_t)b * LOW * IN_DIM;

    int w = t >> 6, lane = t & 63;
    int wm = w >> 1, wn = w & 1;
    int lr = lane & 15, hi = lane >> 4;

    f32x4 acc[4];
#pragma unroll
    for (int nf = 0; nf < 4; ++nf) acc[nf] = (f32x4){0.f, 0.f, 0.f, 0.f};

    int ar = t >> 3, ac = t & 7;
    int brt = t >> 3, bc = t & 7;

    for (int kt = 0; kt < IN_DIM / 64; ++kt) {
        int k0 = kt * 64;
#pragma unroll
        for (int i = 0; i < 2; ++i) {
            float4 v = *(const float4*)(xb + (size_t)ar * IN_DIM + k0 + ac * 4 + i * 32);
            u16x4 o;
            o.x = f2bf(v.x); o.y = f2bf(v.y); o.z = f2bf(v.z); o.w = f2bf(v.w);
            *(u16x4*)(&As[ar][ac * 4 + i * 32]) = o;
        }
#pragma unroll
        for (int i = 0; i < 4; ++i) {
            int row = brt + 32 * i;
            bf16x8 v = *(const bf16x8*)(Db + (size_t)row * IN_DIM + k0 + bc * 8);
            *(bf16x8*)(&Bs[row][bc * 8]) = v;
        }
        __syncthreads();
#pragma unroll
        for (int ks = 0; ks < 2; ++ks) {
            int kk = ks * 32 + hi * 8;
            bf16x8 af = *(const bf16x8*)(&As[wm * 16 + lr][kk]);
#pragma unroll
            for (int nf = 0; nf < 4; ++nf) {
                bf16x8 bf = *(const bf16x8*)(&Bs[wn * 64 + nf * 16 + lr][kk]);
                acc[nf] = __builtin_amdgcn_mfma_f32_16x16x32_bf16(af, bf, acc[nf], 0, 0, 0);
            }
        }
        __syncthreads();
    }
    u16* hb = h + ((size_t)b * SEQ + s0) * LOW;
#pragma unroll
    for (int nf = 0; nf < 4; ++nf) {
        int col = wn * 64 + nf * 16 + lr;
#pragma unroll
        for (int j = 0; j < 4; ++j) {
            int rrow = wm * 16 + hi * 4 + j;
            hb[(size_t)rrow * LOW + col] = f2bf(fmaxf(acc[nf][j], 0.f));
        }
    }
}

// ---------------------------------------------------------------------------
// fc2: out[b][s][o] = sum_l h[b][s][l] * U[b][l][o]   (f32 out)
// tile: 128x128, K=128 staged once. grid = 8*16*8 = 1024
// ---------------------------------------------------------------------------
__global__ __launch_bounds__(256) void fc2(const u16* __restrict__ h,
                                           const u16* __restrict__ UgT,
                                           float* __restrict__ out) {
    __shared__ u16 As[128 * 128];
    __shared__ u16 Bs[128 * 128];
    int t = threadIdx.x;
    int bid = blockIdx.x;
    int b = bid >> 7, st = (bid >> 3) & 15, ot = bid & 7;
    int s0 = st * 128, o0 = ot * 128;
    const u16* hb = h + ((size_t)b * SEQ + s0) * LOW;
    const u16* Ub = UgT + ((size_t)b * OUT_DIM + o0) * LOW;

#pragma unroll
    for (int i = 0; i < 8; ++i) {
        int ch = i * 256 + t;
        int row = ch >> 4, c = ch & 15;
        int swc = c ^ (row & 7);
        *(bf16x8*)(As + row * 128 + swc * 8) = *(const bf16x8*)(hb + (size_t)ch * 8);
        *(bf16x8*)(Bs + row * 128 + swc * 8) = *(const bf16x8*)(Ub + (size_t)ch * 8);
    }
    __syncthreads();

    int w = t >> 6, lane = t & 63;
    int wm = w >> 1, wn = w & 1;
    int lr = lane & 15, lkc = (lane >> 4);

    f32x4 acc[4][4];
#pragma unroll
    for (int mf = 0; mf < 4; ++mf)
#pragma unroll
        for (int nf = 0; nf < 4; ++nf)
            acc[mf][nf] = (f32x4){0.f, 0.f, 0.f, 0.f};

#pragma unroll
    for (int ks = 0; ks < 4; ++ks) {
        bf16x8 af[4], bfr[4];
#pragma unroll
        for (int mf = 0; mf < 4; ++mf) {
            int row = wm * 64 + mf * 16 + lr;
            int swc = (ks * 4 + lkc) ^ (row & 7);
            af[mf] = *(const bf16x8*)(As + row * 128 + swc * 8);
        }
#pragma unroll
        for (int nf = 0; nf < 4; ++nf) {
            int row = wn * 64 + nf * 16 + lr;
            int swc = (ks * 4 + lkc) ^ (row & 7);
            bfr[nf] = *(const bf16x8*)(Bs + row * 128 + swc * 8);
        }
#pragma unroll
        for (int mf = 0; mf < 4; ++mf)
#pragma unroll
            for (int nf = 0; nf < 4; ++nf)
                acc[mf][nf] = __builtin_amdgcn_mfma_f32_16x16x32_bf16(
                    af[mf], bfr[nf], acc[mf][nf], 0, 0, 0);
    }

    float* ob = out + ((size_t)b * SEQ + s0) * OUT_DIM + o0;
#pragma unroll
    for (int mf = 0; mf < 4; ++mf)
#pragma unroll
        for (int nf = 0; nf < 4; ++nf) {
            int col = wn * 64 + nf * 16 + lr;
#pragma unroll
            for (int j = 0; j < 4; ++j) {
                int rrow = wm * 64 + mf * 16 + (lane >> 4) * 4 + j;
                ob[(size_t)rrow * OUT_DIM + col] = acc[mf][nf][j];
            }
        }
}

extern "C" void kernel_launch(void* const* d_in, const int* in_sizes, int n_in,
                              void* d_out, int out_size, void* d_ws, size_t ws_size,
                              hipStream_t stream) {
    const float* x  = (const float*)d_in[0];
    const float* kv = (const float*)d_in[1];
    const float* Dm = (const float*)d_in[2];
    const float* Um = (const float*)d_in[3];
    float* out = (float*)d_out;

    u16* DgT = (u16*)d_ws;                                   // 2 MB
    u16* UgT = DgT + (size_t)BATCH * LOW * IN_DIM;           // 2 MB
    u16* hbuf = UgT + (size_t)BATCH * OUT_DIM * LOW;         // 4 MB

    gen_w<<<dim3(1024), dim3(256), 0, stream>>>(Dm, Um, kv, DgT, UgT);
    fc1<<<dim3(512), dim3(256), 0, stream>>>(x, DgT, hbuf);
    fc2<<<dim3(1024), dim3(256), 0, stream>>>(hbuf, UgT, out);
}